// Round 3
// baseline (3227.235 us; speedup 1.0000x reference)
//
#include <hip/hip_runtime.h>
#include <stdint.h>

#define T_STEPS 200
#define OBSD    128
#define HID     128
#define LATD    32
#define BS_TOT  12800
#define KIN     160

#define OUT_ENT_OFF 81920000
#define OUT_LP_OFF  84480000

typedef short  bf16x8 __attribute__((ext_vector_type(8)));
typedef float  f32x4  __attribute__((ext_vector_type(4)));
typedef uint32_t u32;
typedef u32    u32x4  __attribute__((ext_vector_type(4)));

__device__ __forceinline__ uint16_t f2bf(float f) {
    u32 u = __builtin_bit_cast(u32, f);
    u32 r = (u + 0x7fffu + ((u >> 16) & 1u)) >> 16;
    return (uint16_t)r;
}
__device__ __forceinline__ float bf2f(u32 bits16) {
    u32 u = bits16 << 16;
    return __builtin_bit_cast(float, u);
}
__device__ __forceinline__ u32 pack2(float a, float b) {
    return (u32)f2bf(a) | ((u32)f2bf(b) << 16);
}
__device__ __forceinline__ u32 cvt_pk_bf16(float lo, float hi) {
    u32 r;
    asm("v_cvt_pk_bf16_f32 %0, %1, %2" : "=v"(r) : "v"(lo), "v"(hi));
    return r;
}
__device__ __forceinline__ float fast_sig(float x) {
    return __builtin_amdgcn_rcpf(1.f + __expf(-x));
}
__device__ __forceinline__ float fast_tanh(float x) {
    return 1.f - 2.f * __builtin_amdgcn_rcpf(1.f + __expf(2.f * x));
}

// ---------------------------------------------------------------------------
// Kernel 1: xg[t][bq][tid][8 uint4] = x @ W_ihx^T + b_ih + b_hh (+ zbias for
// t>0), bf16, in the main kernel's fragment order.
// zbias[col] = sum_j b_mu[j] * W_ih[col][128+j]  (the folded b_mu term).
// ---------------------------------------------------------------------------
__global__ __launch_bounds__(512, 2) void xg_prep(
    const float* __restrict__ x,
    const float* __restrict__ W_ih,
    const float* __restrict__ b_ih,
    const float* __restrict__ b_hh,
    const float* __restrict__ b_mu,
    uint16_t* __restrict__ xg)
{
    const int blk = blockIdx.x;
    const int t   = blk >> 2, bq = blk & 3;
    const int tid = threadIdx.x;
    const int w = tid >> 6, l = tid & 63, lg = l >> 4, ln = l & 15;
    const int b0 = bq * 64;

    bf16x8 wb[4][4];
    float  bias[4];
    #pragma unroll
    for (int q = 0; q < 4; ++q) {
        const int col = q * 128 + w * 16 + ln;
        float zb = 0.f;
        #pragma unroll
        for (int j = 0; j < 32; ++j) zb += b_mu[j] * W_ih[col * KIN + 128 + j];
        bias[q] = b_ih[col] + b_hh[col] + (t > 0 ? zb : 0.f);
        #pragma unroll
        for (int ks = 0; ks < 4; ++ks) {
            bf16x8 v;
            #pragma unroll
            for (int e = 0; e < 8; ++e)
                v[e] = (short)f2bf(W_ih[col * KIN + ks * 32 + lg * 8 + e]);
            wb[ks][q] = v;
        }
    }

    f32x4 acc[4][4];
    const f32x4 vz = {0.f, 0.f, 0.f, 0.f};
    #pragma unroll
    for (int rt = 0; rt < 4; ++rt)
        #pragma unroll
        for (int q = 0; q < 4; ++q) acc[rt][q] = vz;

    #pragma unroll
    for (int ks = 0; ks < 4; ++ks) {
        bf16x8 a[4];
        #pragma unroll
        for (int rt = 0; rt < 4; ++rt) {
            const int brow = b0 + rt * 16 + ln;
            const float* src = x + ((size_t)brow * T_STEPS + t) * OBSD + ks * 32 + lg * 8;
            bf16x8 v;
            #pragma unroll
            for (int e = 0; e < 8; ++e) v[e] = (short)f2bf(src[e]);
            a[rt] = v;
        }
        #pragma unroll
        for (int rt = 0; rt < 4; ++rt)
            #pragma unroll
            for (int q = 0; q < 4; ++q)
                acc[rt][q] = __builtin_amdgcn_mfma_f32_16x16x32_bf16(
                    a[rt], wb[ks][q], acc[rt][q], 0, 0, 0);
    }

    uint4* dst = (uint4*)xg + ((size_t)blk * 512 + tid) * 8;
    #pragma unroll
    for (int rt = 0; rt < 4; ++rt) {
        float v0[4], v1[4], v2[4], v3[4];
        #pragma unroll
        for (int e = 0; e < 4; ++e) {
            v0[e] = acc[rt][0][e] + bias[0];
            v1[e] = acc[rt][1][e] + bias[1];
            v2[e] = acc[rt][2][e] + bias[2];
            v3[e] = acc[rt][3][e] + bias[3];
        }
        uint4 o0, o1;
        o0.x = pack2(v0[0], v0[1]); o0.y = pack2(v0[2], v0[3]);
        o0.z = pack2(v1[0], v1[1]); o0.w = pack2(v1[2], v1[3]);
        o1.x = pack2(v2[0], v2[1]); o1.y = pack2(v2[2], v2[3]);
        o1.z = pack2(v3[0], v3[1]); o1.w = pack2(v3[2], v3[3]);
        dst[2 * rt]     = o0;
        dst[2 * rt + 1] = o1;
    }
}

// ---------------------------------------------------------------------------
// Kernel 2: entropies = constant
// ---------------------------------------------------------------------------
__global__ void ent_fill(const float* __restrict__ cov, float* __restrict__ out)
{
    __shared__ float ec;
    if (threadIdx.x == 0) {
        float logdet = 0.f;
        for (int i = 0; i < LATD; ++i) logdet += logf(cov[i]);
        ec = 0.5f * 32.f * (1.f + 1.8378770664093453f) + 0.5f * logdet;
    }
    __syncthreads();
    const int idx = blockIdx.x * blockDim.x + threadIdx.x;
    const int stride = gridDim.x * blockDim.x;
    for (int i = idx; i < 2560000; i += stride)
        out[OUT_ENT_OFF + i] = ec;
}

// ---------------------------------------------------------------------------
// Kernel 3: recurrence. launch_bounds(512,1) -> 256 VGPR budget (no spills).
//   Wr = W_hh + W_ihz @ W_mu ; eg-weights = diag(std) @ W_ihz (std folded in)
//   gates_t = xg_t(+zbias) + eps_{t-1} @ weg^T + h_{t-1} @ Wr^T
//   z_{t-1} = h_{t-1} @ W_mu^T + b_mu + eps_{t-1}*std   (off critical path)
// eps double-buffered in LDS, loaded a full step ahead. 2 barriers/step.
// ---------------------------------------------------------------------------
__global__ __launch_bounds__(512, 1) void lstm_main(
    const float* __restrict__ eps,
    const float* __restrict__ W_ih,
    const float* __restrict__ W_hh,
    const float* __restrict__ W_mu,
    const float* __restrict__ b_mu,
    const float* __restrict__ cov,
    const uint16_t* __restrict__ xg,
    float* __restrict__ out)
{
    __shared__ __align__(16) char smem[64 * 136 * 2 + 2 * 64 * 36 * 4];
    uint16_t* h_lds = (uint16_t*)smem;
    float*    e_lds = (float*)(smem + 64 * 136 * 2);   // [2][64][36]
    float*    wmu_s = (float*)smem;                    // init-time alias

    const int blk = blockIdx.x, bq = blk & 3;
    const int bs0 = blk * 64;
    const int tid = threadIdx.x;
    const int w = tid >> 6, l = tid & 63, lg = l >> 4, ln = l & 15;

    for (int i = tid; i < 4096; i += 512) wmu_s[i] = W_mu[i];
    __syncthreads();

    // ---- build weight fragments ----
    bf16x8 wr[4][4];   // Wr = W_hh + W_ihz @ W_mu
    bf16x8 weg[4];     // diag(std) @ W_ihz  (K=32)
    {
        float stds[8];
        #pragma unroll
        for (int e = 0; e < 8; ++e) stds[e] = sqrtf(cov[lg * 8 + e]);
        #pragma unroll
        for (int q = 0; q < 4; ++q) {
            const int col = q * 128 + w * 16 + ln;
            float wzf[32];
            #pragma unroll
            for (int j4 = 0; j4 < 8; ++j4)
                *(float4*)&wzf[j4 * 4] = *(const float4*)&W_ih[col * KIN + 128 + j4 * 4];
            {
                bf16x8 v;
                #pragma unroll
                for (int e = 0; e < 8; ++e)
                    v[e] = (short)f2bf(wzf[lg * 8 + e] * stds[e]);
                weg[q] = v;
            }
            #pragma unroll
            for (int ks = 0; ks < 4; ++ks) {
                float base[8];
                *(float4*)&base[0] = *(const float4*)&W_hh[col * HID + ks * 32 + lg * 8];
                *(float4*)&base[4] = *(const float4*)&W_hh[col * HID + ks * 32 + lg * 8 + 4];
                bf16x8 v;
                #pragma unroll
                for (int e = 0; e < 8; ++e) {
                    float s = base[e];
                    #pragma unroll
                    for (int j = 0; j < 32; ++j)
                        s += wzf[j] * wmu_s[j * HID + ks * 32 + lg * 8 + e];
                    v[e] = (short)f2bf(s);
                }
                wr[ks][q] = v;
            }
        }
    }

    const int rtm = w >> 1, ctm = w & 1;
    const int zcol = ctm * 16 + ln;
    bf16x8 wmu[4];
    #pragma unroll
    for (int ks = 0; ks < 4; ++ks) {
        bf16x8 v;
        #pragma unroll
        for (int e = 0; e < 8; ++e)
            v[e] = (short)f2bf(wmu_s[zcol * HID + ks * 32 + lg * 8 + e]);
        wmu[ks] = v;
    }
    const float stdv = sqrtf(cov[zcol]);
    const float bmu  = b_mu[zcol];
    float logdet = 0.f;
    for (int i = 0; i < LATD; ++i) logdet += logf(cov[i]);
    const float lconst = 32.f * 1.8378770664093453f + logdet;

    __syncthreads();   // everyone done reading wmu_s

    const int sr = tid >> 3, sc = (tid & 7) * 4;   // eps staging map

    for (int i = tid; i < 64 * 136; i += 512) h_lds[i] = 0;
    // prologue: stage eps_0 into e_lds[0]
    {
        const float4 e0 = *(const float4*)(eps + ((size_t)0 * BS_TOT + bs0 + sr) * LATD + sc);
        *(float4*)&e_lds[sr * 36 + sc] = e0;
    }
    const f32x4 vz4 = {0.f, 0.f, 0.f, 0.f};
    f32x4 cst[4];
    #pragma unroll
    for (int rt = 0; rt < 4; ++rt) cst[rt] = vz4;
    u32x4 epf[4];
    float ev[4];
    __syncthreads();

    for (int t = 0; t < T_STEPS; ++t) {
        // issue next-step eps + this-step xg loads
        float4 ev4 = {0.f, 0.f, 0.f, 0.f};
        if (t + 1 < T_STEPS)
            ev4 = *(const float4*)(eps + ((size_t)(t + 1) * BS_TOT + bs0 + sr) * LATD + sc);
        uint4 xv[8];
        const uint4* xp = (const uint4*)xg + ((size_t)(t * 4 + bq) * 512 + tid) * 8;
        #pragma unroll
        for (int i = 0; i < 8; ++i) xv[i] = xp[i];

        f32x4 acc[4][4];
        #pragma unroll
        for (int rt = 0; rt < 4; ++rt)
            #pragma unroll
            for (int q = 0; q < 4; ++q) acc[rt][q] = vz4;

        if (t > 0) {
            // eg: eps_{t-1} @ weg^T (all-register)
            #pragma unroll
            for (int rt = 0; rt < 4; ++rt) {
                const bf16x8 a = __builtin_bit_cast(bf16x8, epf[rt]);
                #pragma unroll
                for (int q = 0; q < 4; ++q)
                    acc[rt][q] = __builtin_amdgcn_mfma_f32_16x16x32_bf16(
                        a, weg[q], acc[rt][q], 0, 0, 0);
            }
            // gates: h_{t-1} @ Wr^T
            #pragma unroll
            for (int ks = 0; ks < 4; ++ks) {
                bf16x8 a[4];
                #pragma unroll
                for (int rt = 0; rt < 4; ++rt)
                    a[rt] = *(const bf16x8*)&h_lds[(rt * 16 + ln) * 136 + ks * 32 + lg * 8];
                #pragma unroll
                for (int rt = 0; rt < 4; ++rt)
                    #pragma unroll
                    for (int q = 0; q < 4; ++q)
                        acc[rt][q] = __builtin_amdgcn_mfma_f32_16x16x32_bf16(
                            a[rt], wr[ks][q], acc[rt][q], 0, 0, 0);
            }
            // mean/z for step t-1 (off critical path)
            f32x4 macc = vz4;
            #pragma unroll
            for (int ks = 0; ks < 4; ++ks) {
                const bf16x8 am = *(const bf16x8*)&h_lds[(rtm * 16 + ln) * 136 + ks * 32 + lg * 8];
                macc = __builtin_amdgcn_mfma_f32_16x16x32_bf16(am, wmu[ks], macc, 0, 0, 0);
            }
            #pragma unroll
            for (int e = 0; e < 4; ++e) {
                const int row = rtm * 16 + lg * 4 + e;
                out[(size_t)(bs0 + row) * 6400 + (t - 1) * 32 + zcol] =
                    macc[e] + bmu + ev[e] * stdv;
            }
        }

        __syncthreads();   // barA: h_{t-1} reads done

        // ---- LSTM elementwise ----
        #pragma unroll
        for (int rt = 0; rt < 4; ++rt) {
            const uint4 u01 = xv[2 * rt], u23 = xv[2 * rt + 1];
            const float xi[4] = { bf2f(u01.x & 0xffff), bf2f(u01.x >> 16),
                                  bf2f(u01.y & 0xffff), bf2f(u01.y >> 16) };
            const float xf[4] = { bf2f(u01.z & 0xffff), bf2f(u01.z >> 16),
                                  bf2f(u01.w & 0xffff), bf2f(u01.w >> 16) };
            const float xgv[4] = { bf2f(u23.x & 0xffff), bf2f(u23.x >> 16),
                                   bf2f(u23.y & 0xffff), bf2f(u23.y >> 16) };
            const float xo[4] = { bf2f(u23.z & 0xffff), bf2f(u23.z >> 16),
                                  bf2f(u23.w & 0xffff), bf2f(u23.w >> 16) };
            float hv[4];
            #pragma unroll
            for (int e = 0; e < 4; ++e) {
                const float iv = acc[rt][0][e] + xi[e];
                const float fv = acc[rt][1][e] + xf[e];
                const float gv = acc[rt][2][e] + xgv[e];
                const float ov = acc[rt][3][e] + xo[e];
                const float c  = fast_sig(fv) * cst[rt][e] + fast_sig(iv) * fast_tanh(gv);
                cst[rt][e] = c;
                hv[e] = fast_sig(ov) * fast_tanh(c);
            }
            const u32 p01 = cvt_pk_bf16(hv[0], hv[1]);
            const u32 p23 = cvt_pk_bf16(hv[2], hv[3]);
            const int rb = (rt * 16 + lg * 4) * 136 + w * 16 + ln;
            h_lds[rb]       = (uint16_t)p01;
            h_lds[rb + 136] = (uint16_t)(p01 >> 16);
            h_lds[rb + 272] = (uint16_t)p23;
            h_lds[rb + 408] = (uint16_t)(p23 >> 16);
        }

        // ---- eps_t prep (reads e_lds[t&1]) + log-prob(t) ----
        const float* eb = &e_lds[(t & 1) * 64 * 36];
        float ps4[4];
        #pragma unroll
        for (int rt = 0; rt < 4; ++rt) {
            const float* ep = &eb[(rt * 16 + ln) * 36 + lg * 8];
            float er[8];
            *(float4*)&er[0] = *(const float4*)&ep[0];
            *(float4*)&er[4] = *(const float4*)&ep[4];
            float ps = 0.f;
            #pragma unroll
            for (int i = 0; i < 8; ++i) ps += er[i] * er[i];
            ps4[rt] = ps;
            u32x4 pk;
            pk[0] = cvt_pk_bf16(er[0], er[1]);
            pk[1] = cvt_pk_bf16(er[2], er[3]);
            pk[2] = cvt_pk_bf16(er[4], er[5]);
            pk[3] = cvt_pk_bf16(er[6], er[7]);
            epf[rt] = pk;
        }
        #pragma unroll
        for (int rt = 0; rt < 4; ++rt) {
            ps4[rt] += __shfl_xor(ps4[rt], 16, 64);
            ps4[rt] += __shfl_xor(ps4[rt], 32, 64);
        }
        if (w == 0 && lg == 0) {
            #pragma unroll
            for (int rt = 0; rt < 4; ++rt)
                out[OUT_LP_OFF + (size_t)(bs0 + rt * 16 + ln) * 200 + t] =
                    -0.5f * (ps4[rt] + lconst);
        }
        #pragma unroll
        for (int e = 0; e < 4; ++e)
            ev[e] = eb[(rtm * 16 + lg * 4 + e) * 36 + zcol];

        // stage eps_{t+1} into the other buffer (load had a full step to land)
        if (t + 1 < T_STEPS)
            *(float4*)&e_lds[((t + 1) & 1) * 64 * 36 + sr * 36 + sc] = ev4;

        __syncthreads();   // barB: h_t + eps_{t+1} visible
    }

    // epilogue: z for t = 199
    {
        f32x4 macc = vz4;
        #pragma unroll
        for (int ks = 0; ks < 4; ++ks) {
            const bf16x8 am = *(const bf16x8*)&h_lds[(rtm * 16 + ln) * 136 + ks * 32 + lg * 8];
            macc = __builtin_amdgcn_mfma_f32_16x16x32_bf16(am, wmu[ks], macc, 0, 0, 0);
        }
        #pragma unroll
        for (int e = 0; e < 4; ++e) {
            const int row = rtm * 16 + lg * 4 + e;
            out[(size_t)(bs0 + row) * 6400 + 199 * 32 + zcol] =
                macc[e] + bmu + ev[e] * stdv;
        }
    }
}

extern "C" void kernel_launch(void* const* d_in, const int* in_sizes, int n_in,
                              void* d_out, int out_size, void* d_ws, size_t ws_size,
                              hipStream_t stream) {
    const float* x    = (const float*)d_in[0];
    const float* eps  = (const float*)d_in[1];
    const float* W_ih = (const float*)d_in[2];
    const float* W_hh = (const float*)d_in[3];
    const float* b_ih = (const float*)d_in[4];
    const float* b_hh = (const float*)d_in[5];
    const float* W_mu = (const float*)d_in[6];
    const float* b_mu = (const float*)d_in[7];
    const float* cov  = (const float*)d_in[8];
    float* out = (float*)d_out;
    uint16_t* xg = (uint16_t*)d_ws;   // 52,428,800 bytes

    hipLaunchKernelGGL(xg_prep, dim3(800), dim3(512), 0, stream, x, W_ih, b_ih, b_hh, b_mu, xg);
    hipLaunchKernelGGL(ent_fill, dim3(2048), dim3(256), 0, stream, cov, out);
    hipLaunchKernelGGL(lstm_main, dim3(200), dim3(512), 0, stream,
                       eps, W_ih, W_hh, W_mu, b_mu, cov, xg, out);
}

// Round 4
// 1906.825 us; speedup vs baseline: 1.6925x; 1.6925x over previous
//
#include <hip/hip_runtime.h>
#include <stdint.h>

#define T_STEPS 200
#define OBSD    128
#define HID     128
#define LATD    32
#define BS_TOT  12800
#define KIN     160

#define OUT_ENT_OFF 81920000
#define OUT_LP_OFF  84480000

// lstm_main LDS layout (bytes)
#define WR_OFF 0            // 131072 B : Wr bf16 fragments
#define H_OFF  131072       // 16384 B  : h tile [64][128] bf16, XOR-swizzled
#define E_OFF  147456       // 9216 B   : eps stage [64][36] f32
#define LDS_SZ 156672

typedef short  bf16x8 __attribute__((ext_vector_type(8)));
typedef float  f32x4  __attribute__((ext_vector_type(4)));
typedef uint32_t u32;
typedef u32    u32x4  __attribute__((ext_vector_type(4)));

__device__ __forceinline__ uint16_t f2bf(float f) {
    u32 u = __builtin_bit_cast(u32, f);
    u32 r = (u + 0x7fffu + ((u >> 16) & 1u)) >> 16;
    return (uint16_t)r;
}
__device__ __forceinline__ float bf2f(u32 bits16) {
    u32 u = bits16 << 16;
    return __builtin_bit_cast(float, u);
}
__device__ __forceinline__ u32 pack2(float a, float b) {
    return (u32)f2bf(a) | ((u32)f2bf(b) << 16);
}
__device__ __forceinline__ u32 cvt_pk_bf16(float lo, float hi) {
    u32 r;
    asm("v_cvt_pk_bf16_f32 %0, %1, %2" : "=v"(r) : "v"(lo), "v"(hi));
    return r;
}
__device__ __forceinline__ float fast_sig(float x) {
    return __builtin_amdgcn_rcpf(1.f + __expf(-x));
}
__device__ __forceinline__ float fast_tanh(float x) {
    return 1.f - 2.f * __builtin_amdgcn_rcpf(1.f + __expf(2.f * x));
}
// byte offset of h[row][col] inside the H region (XOR bank swizzle)
__device__ __forceinline__ int hswz(int row, int col) {
    return ((row << 8) + (col << 1)) ^ ((row & 7) << 4);
}

// ---------------------------------------------------------------------------
// Kernel 1: xg[t][bq][tid][8 uint4] = x @ W_ihx^T + b_ih + b_hh (+ zbias for
// t>0), bf16, in the main kernel's fragment order. (passing since round 1/3)
// ---------------------------------------------------------------------------
__global__ __launch_bounds__(512, 2) void xg_prep(
    const float* __restrict__ x,
    const float* __restrict__ W_ih,
    const float* __restrict__ b_ih,
    const float* __restrict__ b_hh,
    const float* __restrict__ b_mu,
    uint16_t* __restrict__ xg)
{
    const int blk = blockIdx.x;
    const int t   = blk >> 2, bq = blk & 3;
    const int tid = threadIdx.x;
    const int w = tid >> 6, l = tid & 63, lg = l >> 4, ln = l & 15;
    const int b0 = bq * 64;

    bf16x8 wb[4][4];
    float  bias[4];
    #pragma unroll
    for (int q = 0; q < 4; ++q) {
        const int col = q * 128 + w * 16 + ln;
        float zb = 0.f;
        #pragma unroll
        for (int j = 0; j < 32; ++j) zb += b_mu[j] * W_ih[col * KIN + 128 + j];
        bias[q] = b_ih[col] + b_hh[col] + (t > 0 ? zb : 0.f);
        #pragma unroll
        for (int ks = 0; ks < 4; ++ks) {
            bf16x8 v;
            #pragma unroll
            for (int e = 0; e < 8; ++e)
                v[e] = (short)f2bf(W_ih[col * KIN + ks * 32 + lg * 8 + e]);
            wb[ks][q] = v;
        }
    }

    f32x4 acc[4][4];
    const f32x4 vz = {0.f, 0.f, 0.f, 0.f};
    #pragma unroll
    for (int rt = 0; rt < 4; ++rt)
        #pragma unroll
        for (int q = 0; q < 4; ++q) acc[rt][q] = vz;

    #pragma unroll
    for (int ks = 0; ks < 4; ++ks) {
        bf16x8 a[4];
        #pragma unroll
        for (int rt = 0; rt < 4; ++rt) {
            const int brow = b0 + rt * 16 + ln;
            const float* src = x + ((size_t)brow * T_STEPS + t) * OBSD + ks * 32 + lg * 8;
            bf16x8 v;
            #pragma unroll
            for (int e = 0; e < 8; ++e) v[e] = (short)f2bf(src[e]);
            a[rt] = v;
        }
        #pragma unroll
        for (int rt = 0; rt < 4; ++rt)
            #pragma unroll
            for (int q = 0; q < 4; ++q)
                acc[rt][q] = __builtin_amdgcn_mfma_f32_16x16x32_bf16(
                    a[rt], wb[ks][q], acc[rt][q], 0, 0, 0);
    }

    uint4* dst = (uint4*)xg + ((size_t)blk * 512 + tid) * 8;
    #pragma unroll
    for (int rt = 0; rt < 4; ++rt) {
        float v0[4], v1[4], v2[4], v3[4];
        #pragma unroll
        for (int e = 0; e < 4; ++e) {
            v0[e] = acc[rt][0][e] + bias[0];
            v1[e] = acc[rt][1][e] + bias[1];
            v2[e] = acc[rt][2][e] + bias[2];
            v3[e] = acc[rt][3][e] + bias[3];
        }
        uint4 o0, o1;
        o0.x = pack2(v0[0], v0[1]); o0.y = pack2(v0[2], v0[3]);
        o0.z = pack2(v1[0], v1[1]); o0.w = pack2(v1[2], v1[3]);
        o1.x = pack2(v2[0], v2[1]); o1.y = pack2(v2[2], v2[3]);
        o1.z = pack2(v3[0], v3[1]); o1.w = pack2(v3[2], v3[3]);
        dst[2 * rt]     = o0;
        dst[2 * rt + 1] = o1;
    }
}

// ---------------------------------------------------------------------------
// Kernel 2: entropies = constant
// ---------------------------------------------------------------------------
__global__ void ent_fill(const float* __restrict__ cov, float* __restrict__ out)
{
    __shared__ float ec;
    if (threadIdx.x == 0) {
        float logdet = 0.f;
        for (int i = 0; i < LATD; ++i) logdet += logf(cov[i]);
        ec = 0.5f * 32.f * (1.f + 1.8378770664093453f) + 0.5f * logdet;
    }
    __syncthreads();
    const int idx = blockIdx.x * blockDim.x + threadIdx.x;
    const int stride = gridDim.x * blockDim.x;
    for (int i = idx; i < 2560000; i += stride)
        out[OUT_ENT_OFF + i] = ec;
}

// ---------------------------------------------------------------------------
// Kernel 3: recurrence. Wr in LDS (frees 64 VGPRs), h XOR-swizzled, eps
// single-buffered, lp from load regs. launch_bounds(512) -> 256 VGPR budget.
// ---------------------------------------------------------------------------
__global__ __launch_bounds__(512) void lstm_main(
    const float* __restrict__ eps,
    const float* __restrict__ W_ih,
    const float* __restrict__ W_hh,
    const float* __restrict__ W_mu,
    const float* __restrict__ b_mu,
    const float* __restrict__ cov,
    const uint16_t* __restrict__ xg,
    float* __restrict__ out)
{
    __shared__ __align__(16) char smem[LDS_SZ];

    const int tid = threadIdx.x;
    const int w = tid >> 6, l = tid & 63, lg = l >> 4, ln = l & 15;

    // XCD-aware bijective swizzle: blocks sharing an xg slice (same wk&3)
    // land on the same XCD pair -> xg stays L2-resident.
    const int xcd = blockIdx.x & 7;
    const int wk  = (xcd >> 1) + 4 * ((blockIdx.x >> 3) + 25 * (xcd & 1));
    const int bq  = wk & 3;
    const int bs0 = wk * 64;

    // stage W_mu f32 into the (future) H region for the Wr build
    {
        float* ws = (float*)(smem + H_OFF);
        for (int i = tid; i < 4096; i += 512) ws[i] = W_mu[i];
    }
    __syncthreads();
    const float* wmu_s = (const float*)(smem + H_OFF);

    // ---- build Wr = W_hh + W_ihz @ W_mu into LDS; weg (std-folded) in regs --
    bf16x8 weg[4];
    {
        float stds[8];
        #pragma unroll
        for (int e = 0; e < 8; ++e) stds[e] = sqrtf(cov[lg * 8 + e]);
        #pragma unroll
        for (int q = 0; q < 4; ++q) {
            const int col = q * 128 + w * 16 + ln;
            float wzf[32];
            #pragma unroll
            for (int j4 = 0; j4 < 8; ++j4)
                *(float4*)&wzf[j4 * 4] = *(const float4*)&W_ih[col * KIN + 128 + j4 * 4];
            {
                bf16x8 v;
                #pragma unroll
                for (int e = 0; e < 8; ++e)
                    v[e] = (short)f2bf(wzf[lg * 8 + e] * stds[e]);
                weg[q] = v;
            }
            #pragma unroll
            for (int ks = 0; ks < 4; ++ks) {
                float base[8];
                *(float4*)&base[0] = *(const float4*)&W_hh[col * HID + ks * 32 + lg * 8];
                *(float4*)&base[4] = *(const float4*)&W_hh[col * HID + ks * 32 + lg * 8 + 4];
                bf16x8 v;
                #pragma unroll
                for (int e = 0; e < 8; ++e) {
                    float s = base[e];
                    #pragma unroll
                    for (int j = 0; j < 32; ++j)
                        s += wzf[j] * wmu_s[j * HID + ks * 32 + lg * 8 + e];
                    v[e] = (short)f2bf(s);
                }
                *(bf16x8*)(smem + WR_OFF + (((ks * 4 + q) * 8 + w) << 10) + l * 16) = v;
            }
        }
    }

    // mean-phase constants (wave w -> tile rtm, ctm)
    const int rtm = w >> 1, ctm = w & 1;
    const int zcol = ctm * 16 + ln;
    bf16x8 wmu[4];
    #pragma unroll
    for (int ks = 0; ks < 4; ++ks) {
        bf16x8 v;
        #pragma unroll
        for (int e = 0; e < 8; ++e)
            v[e] = (short)f2bf(wmu_s[zcol * HID + ks * 32 + lg * 8 + e]);
        wmu[ks] = v;
    }
    const float stdv = sqrtf(cov[zcol]);
    const float bmu  = b_mu[zcol];
    float logdet = 0.f;
    for (int i = 0; i < LATD; ++i) logdet += logf(cov[i]);
    const float lconst = 32.f * 1.8378770664093453f + logdet;

    __syncthreads();   // all W_mu/Wr-region reads done

    // zero h tile
    for (int i = tid; i < 4096; i += 512) ((u32*)(smem + H_OFF))[i] = 0;

    // prologue: load eps_0, emit lp(0)
    const int sr = tid >> 3, sc = (tid & 7) * 4;
    float4 ev4c = *(const float4*)(eps + ((size_t)bs0 + sr) * LATD + sc);
    {
        float ps = ev4c.x * ev4c.x + ev4c.y * ev4c.y + ev4c.z * ev4c.z + ev4c.w * ev4c.w;
        ps += __shfl_xor(ps, 1, 64);
        ps += __shfl_xor(ps, 2, 64);
        ps += __shfl_xor(ps, 4, 64);
        if ((l & 7) == 0)
            out[OUT_LP_OFF + (size_t)(bs0 + sr) * 200] = -0.5f * (ps + lconst);
    }
    const f32x4 vz4 = {0.f, 0.f, 0.f, 0.f};
    f32x4 cst[4];
    #pragma unroll
    for (int rt = 0; rt < 4; ++rt) cst[rt] = vz4;
    u32x4 epf[4];
    #pragma unroll
    for (int rt = 0; rt < 4; ++rt) epf[rt] = (u32x4){0, 0, 0, 0};
    float ev[4] = {0.f, 0.f, 0.f, 0.f};
    __syncthreads();   // h zeros + Wr visible

    for (int t = 0; t < T_STEPS; ++t) {
        // ---- P0 ----
        *(float4*)(smem + E_OFF + (sr * 36 + sc) * 4) = ev4c;   // eps_t -> LDS

        float4 ev4n = {0.f, 0.f, 0.f, 0.f};
        if (t < T_STEPS - 1)
            ev4n = *(const float4*)(eps + ((size_t)(t + 1) * BS_TOT + bs0 + sr) * LATD + sc);
        uint4 xv[8];
        const uint4* xp = (const uint4*)xg + ((size_t)(t * 4 + bq) * 512 + tid) * 8;
        #pragma unroll
        for (int i = 0; i < 8; ++i) xv[i] = xp[i];

        f32x4 acc[4][4];
        #pragma unroll
        for (int rt = 0; rt < 4; ++rt)
            #pragma unroll
            for (int q = 0; q < 4; ++q) acc[rt][q] = vz4;

        // eg: eps_{t-1}(bf16) @ (std*W_ihz)^T  (register-only; epf=0 at t=0)
        #pragma unroll
        for (int rt = 0; rt < 4; ++rt) {
            const bf16x8 a = __builtin_bit_cast(bf16x8, epf[rt]);
            #pragma unroll
            for (int q = 0; q < 4; ++q)
                acc[rt][q] = __builtin_amdgcn_mfma_f32_16x16x32_bf16(
                    a, weg[q], acc[rt][q], 0, 0, 0);
        }
        // gates: h_{t-1} @ Wr^T (A from swizzled h, B from Wr LDS)
        #pragma unroll
        for (int ks = 0; ks < 4; ++ks) {
            bf16x8 bfr[4];
            #pragma unroll
            for (int q = 0; q < 4; ++q)
                bfr[q] = *(const bf16x8*)(smem + WR_OFF + (((ks * 4 + q) * 8 + w) << 10) + l * 16);
            bf16x8 a[4];
            #pragma unroll
            for (int rt = 0; rt < 4; ++rt)
                a[rt] = *(const bf16x8*)(smem + H_OFF + hswz(rt * 16 + ln, ks * 32 + lg * 8));
            #pragma unroll
            for (int rt = 0; rt < 4; ++rt)
                #pragma unroll
                for (int q = 0; q < 4; ++q)
                    acc[rt][q] = __builtin_amdgcn_mfma_f32_16x16x32_bf16(
                        a[rt], bfr[q], acc[rt][q], 0, 0, 0);
        }
        // mean/z for t-1 (off critical path)
        if (t > 0) {
            f32x4 macc = vz4;
            #pragma unroll
            for (int ks = 0; ks < 4; ++ks) {
                const bf16x8 am = *(const bf16x8*)(smem + H_OFF + hswz(rtm * 16 + ln, ks * 32 + lg * 8));
                macc = __builtin_amdgcn_mfma_f32_16x16x32_bf16(am, wmu[ks], macc, 0, 0, 0);
            }
            #pragma unroll
            for (int e = 0; e < 4; ++e) {
                const int row = rtm * 16 + lg * 4 + e;
                out[(size_t)(bs0 + row) * 6400 + (t - 1) * 32 + zcol] =
                    macc[e] + bmu + ev[e] * stdv;
            }
        }
        // lp(t+1) straight from the load registers
        if (t < T_STEPS - 1) {
            float ps = ev4n.x * ev4n.x + ev4n.y * ev4n.y + ev4n.z * ev4n.z + ev4n.w * ev4n.w;
            ps += __shfl_xor(ps, 1, 64);
            ps += __shfl_xor(ps, 2, 64);
            ps += __shfl_xor(ps, 4, 64);
            if ((l & 7) == 0)
                out[OUT_LP_OFF + (size_t)(bs0 + sr) * 200 + (t + 1)] = -0.5f * (ps + lconst);
        }

        __syncthreads();   // barA: h/eps reads+writes of P0 settled

        // ---- P1: LSTM elementwise ----
        #pragma unroll
        for (int rt = 0; rt < 4; ++rt) {
            const uint4 u01 = xv[2 * rt], u23 = xv[2 * rt + 1];
            const float xi[4] = { bf2f(u01.x & 0xffff), bf2f(u01.x >> 16),
                                  bf2f(u01.y & 0xffff), bf2f(u01.y >> 16) };
            const float xf[4] = { bf2f(u01.z & 0xffff), bf2f(u01.z >> 16),
                                  bf2f(u01.w & 0xffff), bf2f(u01.w >> 16) };
            const float xgv[4] = { bf2f(u23.x & 0xffff), bf2f(u23.x >> 16),
                                   bf2f(u23.y & 0xffff), bf2f(u23.y >> 16) };
            const float xo[4] = { bf2f(u23.z & 0xffff), bf2f(u23.z >> 16),
                                  bf2f(u23.w & 0xffff), bf2f(u23.w >> 16) };
            #pragma unroll
            for (int e = 0; e < 4; ++e) {
                const float iv = acc[rt][0][e] + xi[e];
                const float fv = acc[rt][1][e] + xf[e];
                const float gv = acc[rt][2][e] + xgv[e];
                const float ov = acc[rt][3][e] + xo[e];
                const float c  = fast_sig(fv) * cst[rt][e] + fast_sig(iv) * fast_tanh(gv);
                cst[rt][e] = c;
                const float h = fast_sig(ov) * fast_tanh(c);
                const int row = rt * 16 + lg * 4 + e;
                *(uint16_t*)(smem + H_OFF + hswz(row, w * 16 + ln)) = f2bf(h);
            }
        }

        // rebuild epf (eps_t bf16 A-frags) + ev (eps_t at mean rows, zcol)
        const float* eb = (const float*)(smem + E_OFF);
        #pragma unroll
        for (int rt = 0; rt < 4; ++rt) {
            const float* ep = eb + (rt * 16 + ln) * 36 + lg * 8;
            float er[8];
            *(float4*)&er[0] = *(const float4*)&ep[0];
            *(float4*)&er[4] = *(const float4*)&ep[4];
            u32x4 pk;
            pk[0] = cvt_pk_bf16(er[0], er[1]);
            pk[1] = cvt_pk_bf16(er[2], er[3]);
            pk[2] = cvt_pk_bf16(er[4], er[5]);
            pk[3] = cvt_pk_bf16(er[6], er[7]);
            epf[rt] = pk;
        }
        #pragma unroll
        for (int e = 0; e < 4; ++e)
            ev[e] = eb[(rtm * 16 + lg * 4 + e) * 36 + zcol];
        ev4c = ev4n;

        __syncthreads();   // barB: h_t visible; e_lds free for next P0 write
    }

    // epilogue: z for t = 199
    {
        f32x4 macc = vz4;
        #pragma unroll
        for (int ks = 0; ks < 4; ++ks) {
            const bf16x8 am = *(const bf16x8*)(smem + H_OFF + hswz(rtm * 16 + ln, ks * 32 + lg * 8));
            macc = __builtin_amdgcn_mfma_f32_16x16x32_bf16(am, wmu[ks], macc, 0, 0, 0);
        }
        #pragma unroll
        for (int e = 0; e < 4; ++e) {
            const int row = rtm * 16 + lg * 4 + e;
            out[(size_t)(bs0 + row) * 6400 + 199 * 32 + zcol] =
                macc[e] + bmu + ev[e] * stdv;
        }
    }
}

extern "C" void kernel_launch(void* const* d_in, const int* in_sizes, int n_in,
                              void* d_out, int out_size, void* d_ws, size_t ws_size,
                              hipStream_t stream) {
    const float* x    = (const float*)d_in[0];
    const float* eps  = (const float*)d_in[1];
    const float* W_ih = (const float*)d_in[2];
    const float* W_hh = (const float*)d_in[3];
    const float* b_ih = (const float*)d_in[4];
    const float* b_hh = (const float*)d_in[5];
    const float* W_mu = (const float*)d_in[6];
    const float* b_mu = (const float*)d_in[7];
    const float* cov  = (const float*)d_in[8];
    float* out = (float*)d_out;
    uint16_t* xg = (uint16_t*)d_ws;   // 52,428,800 bytes

    hipLaunchKernelGGL(xg_prep, dim3(800), dim3(512), 0, stream, x, W_ih, b_ih, b_hh, b_mu, xg);
    hipLaunchKernelGGL(ent_fill, dim3(2048), dim3(256), 0, stream, cov, out);
    hipLaunchKernelGGL(lstm_main, dim3(200), dim3(512), 0, stream,
                       eps, W_ih, W_hh, W_mu, b_mu, cov, xg, out);
}

// Round 6
// 1811.234 us; speedup vs baseline: 1.7818x; 1.0528x over previous
//
#include <hip/hip_runtime.h>
#include <stdint.h>

#define T_STEPS 200
#define OBSD    128
#define HID     128
#define LATD    32
#define BS_TOT  12800
#define KIN     160

#define OUT_ENT_OFF 81920000
#define OUT_LP_OFF  84480000

// lstm_main LDS layout (bytes)
#define WR_OFF  0          // 131072 : Wr bf16 fragments (lane-linear)
#define H_OFF   131072     // 16384  : h tile [64][128] bf16, XOR-swizzled
#define WMU_OFF 147456     // 8192   : W_mu bf16 [32][128], XOR-swizzled
#define E_OFF   155648     // 4096   : eps_{t-1} bf16, A-fragment order
#define LDS_SZ  159744

#define L2E  1.4426950408889634f
#define L2E2 2.8853900817779268f
#define LOG2PI 1.8378770664093453f

typedef short  bf16x8 __attribute__((ext_vector_type(8)));
typedef float  f32x4  __attribute__((ext_vector_type(4)));
typedef uint32_t u32;

__device__ __forceinline__ uint16_t f2bf(float f) {
    u32 u = __builtin_bit_cast(u32, f);
    u32 r = (u + 0x7fffu + ((u >> 16) & 1u)) >> 16;
    return (uint16_t)r;
}
__device__ __forceinline__ float bf2f(u32 bits16) {
    u32 u = bits16 << 16;
    return __builtin_bit_cast(float, u);
}
__device__ __forceinline__ u32 pack2(float a, float b) {
    return (u32)f2bf(a) | ((u32)f2bf(b) << 16);
}
__device__ __forceinline__ u32 cvt_pk_bf16(float lo, float hi) {
    u32 r;
    asm("v_cvt_pk_bf16_f32 %0, %1, %2" : "=v"(r) : "v"(lo), "v"(hi));
    return r;
}
// x pre-scaled by L2E: sigmoid(x_true)
__device__ __forceinline__ float sig2(float x) {
    float e;
    asm("v_exp_f32 %0, -%1" : "=v"(e) : "v"(x));
    return __builtin_amdgcn_rcpf(1.f + e);
}
// x pre-scaled by 2*L2E: tanh(x_true)
__device__ __forceinline__ float tanh2(float x) {
    float e;
    asm("v_exp_f32 %0, %1" : "=v"(e) : "v"(x));
    return 1.f - 2.f * __builtin_amdgcn_rcpf(1.f + e);
}
// byte offset of h[row][col] in a [R][128] bf16 tile, XOR bank swizzle
__device__ __forceinline__ int hswz(int row, int col) {
    return ((row << 8) + (col << 1)) ^ ((row & 7) << 4);
}

// ---------------------------------------------------------------------------
// Kernel 1: xg = (x @ W_ihx^T + b_ih + b_hh + [t>0] zbias) * gate_scale, bf16,
// in the main kernel's fragment order. gate_scale = log2e (i,f,o) / 2log2e (g)
// so the main kernel can use raw v_exp_f32.
// ---------------------------------------------------------------------------
__global__ __launch_bounds__(512, 2) void xg_prep(
    const float* __restrict__ x,
    const float* __restrict__ W_ih,
    const float* __restrict__ b_ih,
    const float* __restrict__ b_hh,
    const float* __restrict__ b_mu,
    uint16_t* __restrict__ xg)
{
    const int blk = blockIdx.x;
    const int t   = blk >> 2, bq = blk & 3;
    const int tid = threadIdx.x;
    const int w = tid >> 6, l = tid & 63, lg = l >> 4, ln = l & 15;
    const int b0 = bq * 64;

    bf16x8 wb[4][4];
    float  bias[4];
    #pragma unroll
    for (int q = 0; q < 4; ++q) {
        const int col = q * 128 + w * 16 + ln;
        float zb = 0.f;
        #pragma unroll
        for (int j = 0; j < 32; ++j) zb += b_mu[j] * W_ih[col * KIN + 128 + j];
        bias[q] = b_ih[col] + b_hh[col] + (t > 0 ? zb : 0.f);
        #pragma unroll
        for (int ks = 0; ks < 4; ++ks) {
            bf16x8 v;
            #pragma unroll
            for (int e = 0; e < 8; ++e)
                v[e] = (short)f2bf(W_ih[col * KIN + ks * 32 + lg * 8 + e]);
            wb[ks][q] = v;
        }
    }

    f32x4 acc[4][4];
    const f32x4 vz = {0.f, 0.f, 0.f, 0.f};
    #pragma unroll
    for (int rt = 0; rt < 4; ++rt)
        #pragma unroll
        for (int q = 0; q < 4; ++q) acc[rt][q] = vz;

    #pragma unroll
    for (int ks = 0; ks < 4; ++ks) {
        bf16x8 a[4];
        #pragma unroll
        for (int rt = 0; rt < 4; ++rt) {
            const int brow = b0 + rt * 16 + ln;
            const float* src = x + ((size_t)brow * T_STEPS + t) * OBSD + ks * 32 + lg * 8;
            bf16x8 v;
            #pragma unroll
            for (int e = 0; e < 8; ++e) v[e] = (short)f2bf(src[e]);
            a[rt] = v;
        }
        #pragma unroll
        for (int rt = 0; rt < 4; ++rt)
            #pragma unroll
            for (int q = 0; q < 4; ++q)
                acc[rt][q] = __builtin_amdgcn_mfma_f32_16x16x32_bf16(
                    a[rt], wb[ks][q], acc[rt][q], 0, 0, 0);
    }

    const float gsc[4] = {L2E, L2E, L2E2, L2E};
    uint4* dst = (uint4*)xg + ((size_t)blk * 512 + tid) * 8;
    #pragma unroll
    for (int rt = 0; rt < 4; ++rt) {
        float v0[4], v1[4], v2[4], v3[4];
        #pragma unroll
        for (int e = 0; e < 4; ++e) {
            v0[e] = (acc[rt][0][e] + bias[0]) * gsc[0];
            v1[e] = (acc[rt][1][e] + bias[1]) * gsc[1];
            v2[e] = (acc[rt][2][e] + bias[2]) * gsc[2];
            v3[e] = (acc[rt][3][e] + bias[3]) * gsc[3];
        }
        uint4 o0, o1;
        o0.x = pack2(v0[0], v0[1]); o0.y = pack2(v0[2], v0[3]);
        o0.z = pack2(v1[0], v1[1]); o0.w = pack2(v1[2], v1[3]);
        o1.x = pack2(v2[0], v2[1]); o1.y = pack2(v2[2], v2[3]);
        o1.z = pack2(v3[0], v3[1]); o1.w = pack2(v3[2], v3[3]);
        dst[2 * rt]     = o0;
        dst[2 * rt + 1] = o1;
    }
}

// ---------------------------------------------------------------------------
// Kernel 2: entropies (const) + log_probs (eps-only) — fully parallel.
// ---------------------------------------------------------------------------
__global__ __launch_bounds__(256) void lp_ent(
    const float* __restrict__ eps,
    const float* __restrict__ cov,
    float* __restrict__ out)
{
    const int blk = blockIdx.x;
    const int rc = blk >> 2, tq = blk & 3;
    const int tid = threadIdx.x;
    const int c = tid & 3, rl = tid >> 2;
    const int row = rc * 64 + rl;

    float logdet = 0.f;
    for (int i = 0; i < LATD; ++i) logdet += logf(cov[i]);
    const float lconst = 32.f * LOG2PI + logdet;
    const float ec = 0.5f * 32.f * (1.f + LOG2PI) + 0.5f * logdet;

    const int t0 = tq * 50;
    for (int t = t0; t < t0 + 50; ++t) {
        const float* ep = eps + ((size_t)t * BS_TOT + row) * LATD + c * 8;
        const float4 a0 = *(const float4*)ep;
        const float4 a1 = *(const float4*)(ep + 4);
        float ps = a0.x*a0.x + a0.y*a0.y + a0.z*a0.z + a0.w*a0.w
                 + a1.x*a1.x + a1.y*a1.y + a1.z*a1.z + a1.w*a1.w;
        ps += __shfl_xor(ps, 1, 64);
        ps += __shfl_xor(ps, 2, 64);
        if (c == 0) {
            out[OUT_LP_OFF  + (size_t)row * 200 + t] = -0.5f * (ps + lconst);
            out[OUT_ENT_OFF + (size_t)row * 200 + t] = ec;
        }
    }
}

// ---------------------------------------------------------------------------
// Kernel 3: recurrence. 200 blocks x 1024 threads (16 waves, 4/SIMD, 128 VGPR
// cap). eps lives in LDS (bf16 A-fragment order) — no register eps state.
// ---------------------------------------------------------------------------
__global__ __launch_bounds__(1024, 4) void lstm_main(
    const float* __restrict__ eps,
    const float* __restrict__ W_ih,
    const float* __restrict__ W_hh,
    const float* __restrict__ W_mu,
    const float* __restrict__ b_mu,
    const float* __restrict__ cov,
    const uint16_t* __restrict__ xg,
    float* __restrict__ out)
{
    __shared__ __align__(16) char smem[LDS_SZ];

    const int tid = threadIdx.x;
    const int w = tid >> 6, l = tid & 63, lg = l >> 4, ln = l & 15;
    const int wp = w & 7, half = w >> 3;

    // XCD-aware bijective swizzle: same-bq blocks share an XCD pair
    const int xcd = blockIdx.x & 7;
    const int wk  = (xcd >> 1) + 4 * ((blockIdx.x >> 3) + 25 * (xcd & 1));
    const int bq  = wk & 3;
    const int bs0 = wk * 64;

    // stage W_mu f32 into the (future) H region
    {
        float* ws = (float*)(smem + H_OFF);
        for (int i = tid; i < 4096; i += 1024) ws[i] = W_mu[i];
    }
    __syncthreads();
    const float* wmu_s = (const float*)(smem + H_OFF);

    // W_mu bf16 region (swizzled), for the mean MFMA B-operand.
    // 2048 u32 words, 1024 threads -> loop twice (round-5 bug was `if`).
    for (int i = tid; i < 2048; i += 1024) {
        const int col = i >> 6, k2 = (i & 63) * 2;
        const u32 p = pack2(wmu_s[col * HID + k2], wmu_s[col * HID + k2 + 1]);
        *(u32*)(smem + WMU_OFF + (((col << 8) + (k2 << 1)) ^ ((col & 7) << 4))) = p;
    }

    // weg = std * W_ihz * gate_scale (B-frags, K=32), all 4 q, in regs
    bf16x8 weg[4];
    {
        float stds[8];
        #pragma unroll
        for (int e = 0; e < 8; ++e) stds[e] = sqrtf(cov[lg * 8 + e]);
        const float gsc[4] = {L2E, L2E, L2E2, L2E};
        #pragma unroll
        for (int q = 0; q < 4; ++q) {
            const int col = q * 128 + wp * 16 + ln;
            bf16x8 v;
            #pragma unroll
            for (int e = 0; e < 8; ++e)
                v[e] = (short)f2bf(W_ih[col * KIN + 128 + lg * 8 + e] * stds[e] * gsc[q]);
            weg[q] = v;
        }
    }

    // Wr = (W_hh + W_ihz @ W_mu) * gate_scale -> LDS. half0: q{0,1}, half1: q{2,3}
    #pragma unroll
    for (int qq = 0; qq < 2; ++qq) {
        const int q = half * 2 + qq;
        const float gs = (q == 2) ? L2E2 : L2E;
        const int col = q * 128 + wp * 16 + ln;
        float wzf[32];
        #pragma unroll
        for (int j4 = 0; j4 < 8; ++j4)
            *(float4*)&wzf[j4 * 4] = *(const float4*)&W_ih[col * KIN + 128 + j4 * 4];
        #pragma unroll
        for (int ks = 0; ks < 4; ++ks) {
            float base[8];
            *(float4*)&base[0] = *(const float4*)&W_hh[col * HID + ks * 32 + lg * 8];
            *(float4*)&base[4] = *(const float4*)&W_hh[col * HID + ks * 32 + lg * 8 + 4];
            bf16x8 v;
            #pragma unroll
            for (int e = 0; e < 8; ++e) {
                float s = base[e];
                #pragma unroll
                for (int j = 0; j < 32; ++j)
                    s += wzf[j] * wmu_s[j * HID + ks * 32 + lg * 8 + e];
                v[e] = (short)f2bf(s * gs);
            }
            *(bf16x8*)(smem + WR_OFF + (((ks * 4 + q) * 8 + wp) << 10) + l * 16) = v;
        }
    }

    // mean-phase constants (meaningful for half==0 waves)
    const int rtm = (w >> 1) & 3, ctm = w & 1;
    const int zcol = ctm * 16 + ln;
    const float stdv = sqrtf(cov[zcol]);
    const float bmu  = b_mu[zcol];

    __syncthreads();   // Wr/WMU written; wmu_s reads done

    // zero h tile (overwrites wmu_s region) and E region
    for (int i = tid; i < 4096; i += 1024) ((u32*)(smem + H_OFF))[i] = 0;
    for (int i = tid; i < 1024; i += 1024) ((u32*)(smem + E_OFF))[i] = 0;

    const f32x4 vz4 = {0.f, 0.f, 0.f, 0.f};
    f32x4 cst[2] = {vz4, vz4};

    // eps load/store maps (thread -> (row, colpair) -> fragment-order byte)
    const int erow = tid >> 4, ecol = (tid & 15) * 2;
    const int ewr = ((erow >> 4) * 64 + (ecol >> 3) * 16 + (erow & 15)) * 16 + (ecol & 7) * 2;

    __syncthreads();   // h zeros + E zeros visible

    for (int t = 0; t < T_STEPS; ++t) {
        // ---- P0: issue global loads ----
        uint4 xv[4];
        const uint4* xp = (const uint4*)xg
            + ((size_t)(t * 4 + bq) * 512 + wp * 64 + l) * 8 + half * 4;
        #pragma unroll
        for (int i = 0; i < 4; ++i) xv[i] = xp[i];
        const float2 fev = *(const float2*)(eps + ((size_t)t * BS_TOT + bs0 + erow) * LATD + ecol);

        // eg: eps_{t-1} @ weg^T  (A-frags straight from E region; zeros at t=0)
        f32x4 acc[2][4];
        #pragma unroll
        for (int rt = 0; rt < 2; ++rt) {
            const bf16x8 aE = *(const bf16x8*)(smem + E_OFF + (((half * 2 + rt) * 64 + l) << 4));
            #pragma unroll
            for (int q = 0; q < 4; ++q)
                acc[rt][q] = __builtin_amdgcn_mfma_f32_16x16x32_bf16(
                    aE, weg[q], vz4, 0, 0, 0);
        }
        // gates: h_{t-1} @ Wr^T
        #pragma unroll
        for (int ks = 0; ks < 4; ++ks) {
            bf16x8 bfr[4];
            #pragma unroll
            for (int q = 0; q < 4; ++q)
                bfr[q] = *(const bf16x8*)(smem + WR_OFF + (((ks * 4 + q) * 8 + wp) << 10) + l * 16);
            bf16x8 a[2];
            #pragma unroll
            for (int rt = 0; rt < 2; ++rt)
                a[rt] = *(const bf16x8*)(smem + H_OFF + hswz((half * 2 + rt) * 16 + ln, ks * 32 + lg * 8));
            #pragma unroll
            for (int rt = 0; rt < 2; ++rt)
                #pragma unroll
                for (int q = 0; q < 4; ++q)
                    acc[rt][q] = __builtin_amdgcn_mfma_f32_16x16x32_bf16(
                        a[rt], bfr[q], acc[rt][q], 0, 0, 0);
        }
        // mean/z for t-1 (half0 waves, off critical path); ev from E (eps_{t-1})
        if (half == 0 && t > 0) {
            f32x4 macc = vz4;
            #pragma unroll
            for (int ks = 0; ks < 4; ++ks) {
                const bf16x8 am = *(const bf16x8*)(smem + H_OFF + hswz(rtm * 16 + ln, ks * 32 + lg * 8));
                const bf16x8 bm = *(const bf16x8*)(smem + WMU_OFF + hswz(zcol, ks * 32 + lg * 8));
                macc = __builtin_amdgcn_mfma_f32_16x16x32_bf16(am, bm, macc, 0, 0, 0);
            }
            #pragma unroll
            for (int e = 0; e < 4; ++e) {
                const int row = rtm * 16 + lg * 4 + e;
                const int eb = (rtm * 64 + (zcol >> 3) * 16 + (lg * 4 + e)) * 16 + (zcol & 7) * 2;
                const float evv = bf2f(*(const uint16_t*)(smem + E_OFF + eb));
                out[(size_t)(bs0 + row) * 6400 + (t - 1) * 32 + zcol] =
                    macc[e] + bmu + evv * stdv;
            }
        }

        __syncthreads();   // barA: all E/h reads of P0 done

        // ---- P1: store eps_t into E (for step t+1) ----
        *(u32*)(smem + E_OFF + ewr) = cvt_pk_bf16(fev.x, fev.y);

        // LSTM elementwise (gates pre-scaled by log2e / 2log2e)
        #pragma unroll
        for (int rt = 0; rt < 2; ++rt) {
            const uint4 u01 = xv[2 * rt], u23 = xv[2 * rt + 1];
            const float xi[4] = { bf2f(u01.x & 0xffff), bf2f(u01.x >> 16),
                                  bf2f(u01.y & 0xffff), bf2f(u01.y >> 16) };
            const float xf[4] = { bf2f(u01.z & 0xffff), bf2f(u01.z >> 16),
                                  bf2f(u01.w & 0xffff), bf2f(u01.w >> 16) };
            const float xgv[4] = { bf2f(u23.x & 0xffff), bf2f(u23.x >> 16),
                                   bf2f(u23.y & 0xffff), bf2f(u23.y >> 16) };
            const float xo[4] = { bf2f(u23.z & 0xffff), bf2f(u23.z >> 16),
                                  bf2f(u23.w & 0xffff), bf2f(u23.w >> 16) };
            #pragma unroll
            for (int e = 0; e < 4; ++e) {
                const float iv = acc[rt][0][e] + xi[e];
                const float fv = acc[rt][1][e] + xf[e];
                const float gv = acc[rt][2][e] + xgv[e];
                const float ov = acc[rt][3][e] + xo[e];
                const float c  = sig2(fv) * cst[rt][e] + sig2(iv) * tanh2(gv);
                cst[rt][e] = c;
                const float h = sig2(ov) * tanh2(c * L2E2);
                const int row = (half * 2 + rt) * 16 + lg * 4 + e;
                *(uint16_t*)(smem + H_OFF + hswz(row, wp * 16 + ln)) = f2bf(h);
            }
        }

        __syncthreads();   // barB: h_t + eps_t visible
    }

    // epilogue: z for t = 199 (E holds eps_199, h holds h_199)
    if (half == 0) {
        f32x4 macc = vz4;
        #pragma unroll
        for (int ks = 0; ks < 4; ++ks) {
            const bf16x8 am = *(const bf16x8*)(smem + H_OFF + hswz(rtm * 16 + ln, ks * 32 + lg * 8));
            const bf16x8 bm = *(const bf16x8*)(smem + WMU_OFF + hswz(zcol, ks * 32 + lg * 8));
            macc = __builtin_amdgcn_mfma_f32_16x16x32_bf16(am, bm, macc, 0, 0, 0);
        }
        #pragma unroll
        for (int e = 0; e < 4; ++e) {
            const int row = rtm * 16 + lg * 4 + e;
            const int eb = (rtm * 64 + (zcol >> 3) * 16 + (lg * 4 + e)) * 16 + (zcol & 7) * 2;
            const float evv = bf2f(*(const uint16_t*)(smem + E_OFF + eb));
            out[(size_t)(bs0 + row) * 6400 + 199 * 32 + zcol] =
                macc[e] + bmu + evv * stdv;
        }
    }
}

extern "C" void kernel_launch(void* const* d_in, const int* in_sizes, int n_in,
                              void* d_out, int out_size, void* d_ws, size_t ws_size,
                              hipStream_t stream) {
    const float* x    = (const float*)d_in[0];
    const float* eps  = (const float*)d_in[1];
    const float* W_ih = (const float*)d_in[2];
    const float* W_hh = (const float*)d_in[3];
    const float* b_ih = (const float*)d_in[4];
    const float* b_hh = (const float*)d_in[5];
    const float* W_mu = (const float*)d_in[6];
    const float* b_mu = (const float*)d_in[7];
    const float* cov  = (const float*)d_in[8];
    float* out = (float*)d_out;
    uint16_t* xg = (uint16_t*)d_ws;   // 52,428,800 bytes

    hipLaunchKernelGGL(xg_prep, dim3(800), dim3(512), 0, stream, x, W_ih, b_ih, b_hh, b_mu, xg);
    hipLaunchKernelGGL(lp_ent, dim3(800), dim3(256), 0, stream, eps, cov, out);
    hipLaunchKernelGGL(lstm_main, dim3(200), dim3(1024), 0, stream,
                       eps, W_ih, W_hh, W_mu, b_mu, cov, xg, out);
}

// Round 7
// 1481.613 us; speedup vs baseline: 2.1782x; 1.2225x over previous
//
#include <hip/hip_runtime.h>
#include <stdint.h>

#define T_STEPS 200
#define OBSD    128
#define HID     128
#define LATD    32
#define BS_TOT  12800
#define KIN     160

#define OUT_ENT_OFF 81920000
#define OUT_LP_OFF  84480000

// lstm_main LDS layout (bytes)
#define WR_OFF  0          // 131072 : Wr bf16 fragments (lane-linear)
#define H_OFF   131072     // 16384  : h tile [64][128] bf16, XOR-swizzled
#define WMU_OFF 147456     // 8192   : W_mu bf16 [32][128], XOR-swizzled
#define E_OFF   155648     // 4096   : eps_{t-1} bf16, A-fragment order
#define LDS_SZ  159744

#define L2E  1.4426950408889634f
#define L2E2 2.8853900817779268f
#define LOG2PI 1.8378770664093453f

typedef short  bf16x8 __attribute__((ext_vector_type(8)));
typedef float  f32x4  __attribute__((ext_vector_type(4)));
typedef uint32_t u32;

// raw workgroup barrier: order LDS only, leave global loads/stores in flight
#define BAR() do {                                        \
    __builtin_amdgcn_sched_barrier(0);                    \
    asm volatile("s_waitcnt lgkmcnt(0)" ::: "memory");    \
    __builtin_amdgcn_s_barrier();                         \
    __builtin_amdgcn_sched_barrier(0);                    \
} while (0)

__device__ __forceinline__ uint16_t f2bf(float f) {
    u32 u = __builtin_bit_cast(u32, f);
    u32 r = (u + 0x7fffu + ((u >> 16) & 1u)) >> 16;
    return (uint16_t)r;
}
__device__ __forceinline__ float bf2f(u32 bits16) {
    u32 u = bits16 << 16;
    return __builtin_bit_cast(float, u);
}
__device__ __forceinline__ u32 pack2(float a, float b) {
    return (u32)f2bf(a) | ((u32)f2bf(b) << 16);
}
__device__ __forceinline__ u32 cvt_pk_bf16(float lo, float hi) {
    u32 r;
    asm("v_cvt_pk_bf16_f32 %0, %1, %2" : "=v"(r) : "v"(lo), "v"(hi));
    return r;
}
// x pre-scaled by L2E: sigmoid(x_true)
__device__ __forceinline__ float sig2(float x) {
    float e;
    asm("v_exp_f32 %0, -%1" : "=v"(e) : "v"(x));
    return __builtin_amdgcn_rcpf(1.f + e);
}
// x pre-scaled by 2*L2E: tanh(x_true)
__device__ __forceinline__ float tanh2(float x) {
    float e;
    asm("v_exp_f32 %0, %1" : "=v"(e) : "v"(x));
    return 1.f - 2.f * __builtin_amdgcn_rcpf(1.f + e);
}
// byte offset of h[row][col] in a [R][128] bf16 tile, XOR bank swizzle
__device__ __forceinline__ int hswz(int row, int col) {
    return ((row << 8) + (col << 1)) ^ ((row & 7) << 4);
}

// ---------------------------------------------------------------------------
// Kernel 1: xg = (x @ W_ihx^T + b_ih + b_hh + [t>0] zbias) * gate_scale, bf16,
// in the main kernel's fragment order.
// ---------------------------------------------------------------------------
__global__ __launch_bounds__(512, 2) void xg_prep(
    const float* __restrict__ x,
    const float* __restrict__ W_ih,
    const float* __restrict__ b_ih,
    const float* __restrict__ b_hh,
    const float* __restrict__ b_mu,
    uint16_t* __restrict__ xg)
{
    const int blk = blockIdx.x;
    const int t   = blk >> 2, bq = blk & 3;
    const int tid = threadIdx.x;
    const int w = tid >> 6, l = tid & 63, lg = l >> 4, ln = l & 15;
    const int b0 = bq * 64;

    bf16x8 wb[4][4];
    float  bias[4];
    #pragma unroll
    for (int q = 0; q < 4; ++q) {
        const int col = q * 128 + w * 16 + ln;
        float zb = 0.f;
        #pragma unroll
        for (int j = 0; j < 32; ++j) zb += b_mu[j] * W_ih[col * KIN + 128 + j];
        bias[q] = b_ih[col] + b_hh[col] + (t > 0 ? zb : 0.f);
        #pragma unroll
        for (int ks = 0; ks < 4; ++ks) {
            bf16x8 v;
            #pragma unroll
            for (int e = 0; e < 8; ++e)
                v[e] = (short)f2bf(W_ih[col * KIN + ks * 32 + lg * 8 + e]);
            wb[ks][q] = v;
        }
    }

    f32x4 acc[4][4];
    const f32x4 vz = {0.f, 0.f, 0.f, 0.f};
    #pragma unroll
    for (int rt = 0; rt < 4; ++rt)
        #pragma unroll
        for (int q = 0; q < 4; ++q) acc[rt][q] = vz;

    #pragma unroll
    for (int ks = 0; ks < 4; ++ks) {
        bf16x8 a[4];
        #pragma unroll
        for (int rt = 0; rt < 4; ++rt) {
            const int brow = b0 + rt * 16 + ln;
            const float* src = x + ((size_t)brow * T_STEPS + t) * OBSD + ks * 32 + lg * 8;
            bf16x8 v;
            #pragma unroll
            for (int e = 0; e < 8; ++e) v[e] = (short)f2bf(src[e]);
            a[rt] = v;
        }
        #pragma unroll
        for (int rt = 0; rt < 4; ++rt)
            #pragma unroll
            for (int q = 0; q < 4; ++q)
                acc[rt][q] = __builtin_amdgcn_mfma_f32_16x16x32_bf16(
                    a[rt], wb[ks][q], acc[rt][q], 0, 0, 0);
    }

    const float gsc[4] = {L2E, L2E, L2E2, L2E};
    uint4* dst = (uint4*)xg + ((size_t)blk * 512 + tid) * 8;
    #pragma unroll
    for (int rt = 0; rt < 4; ++rt) {
        float v0[4], v1[4], v2[4], v3[4];
        #pragma unroll
        for (int e = 0; e < 4; ++e) {
            v0[e] = (acc[rt][0][e] + bias[0]) * gsc[0];
            v1[e] = (acc[rt][1][e] + bias[1]) * gsc[1];
            v2[e] = (acc[rt][2][e] + bias[2]) * gsc[2];
            v3[e] = (acc[rt][3][e] + bias[3]) * gsc[3];
        }
        uint4 o0, o1;
        o0.x = pack2(v0[0], v0[1]); o0.y = pack2(v0[2], v0[3]);
        o0.z = pack2(v1[0], v1[1]); o0.w = pack2(v1[2], v1[3]);
        o1.x = pack2(v2[0], v2[1]); o1.y = pack2(v2[2], v2[3]);
        o1.z = pack2(v3[0], v3[1]); o1.w = pack2(v3[2], v3[3]);
        dst[2 * rt]     = o0;
        dst[2 * rt + 1] = o1;
    }
}

// ---------------------------------------------------------------------------
// Kernel 2: entropies (const) + log_probs (eps-only) — fully parallel.
// ---------------------------------------------------------------------------
__global__ __launch_bounds__(256) void lp_ent(
    const float* __restrict__ eps,
    const float* __restrict__ cov,
    float* __restrict__ out)
{
    const int blk = blockIdx.x;
    const int rc = blk >> 2, tq = blk & 3;
    const int tid = threadIdx.x;
    const int c = tid & 3, rl = tid >> 2;
    const int row = rc * 64 + rl;

    float logdet = 0.f;
    for (int i = 0; i < LATD; ++i) logdet += logf(cov[i]);
    const float lconst = 32.f * LOG2PI + logdet;
    const float ec = 0.5f * 32.f * (1.f + LOG2PI) + 0.5f * logdet;

    const int t0 = tq * 50;
    for (int t = t0; t < t0 + 50; ++t) {
        const float* ep = eps + ((size_t)t * BS_TOT + row) * LATD + c * 8;
        const float4 a0 = *(const float4*)ep;
        const float4 a1 = *(const float4*)(ep + 4);
        float ps = a0.x*a0.x + a0.y*a0.y + a0.z*a0.z + a0.w*a0.w
                 + a1.x*a1.x + a1.y*a1.y + a1.z*a1.z + a1.w*a1.w;
        ps += __shfl_xor(ps, 1, 64);
        ps += __shfl_xor(ps, 2, 64);
        if (c == 0) {
            out[OUT_LP_OFF  + (size_t)row * 200 + t] = -0.5f * (ps + lconst);
            out[OUT_ENT_OFF + (size_t)row * 200 + t] = ec;
        }
    }
}

// ---------------------------------------------------------------------------
// Kernel 3: recurrence. Same dataflow as round 6; raw lgkm-only barriers
// (no vmcnt drain) + software-pipelined ks-loop (LDS latency under MFMA).
// ---------------------------------------------------------------------------
__global__ __launch_bounds__(1024, 4) void lstm_main(
    const float* __restrict__ eps,
    const float* __restrict__ W_ih,
    const float* __restrict__ W_hh,
    const float* __restrict__ W_mu,
    const float* __restrict__ b_mu,
    const float* __restrict__ cov,
    const uint16_t* __restrict__ xg,
    float* __restrict__ out)
{
    __shared__ __align__(16) char smem[LDS_SZ];

    const int tid = threadIdx.x;
    const int w = tid >> 6, l = tid & 63, lg = l >> 4, ln = l & 15;
    const int wp = w & 7, half = w >> 3;

    // XCD-aware bijective swizzle: same-bq blocks share an XCD pair
    const int xcd = blockIdx.x & 7;
    const int wk  = (xcd >> 1) + 4 * ((blockIdx.x >> 3) + 25 * (xcd & 1));
    const int bq  = wk & 3;
    const int bs0 = wk * 64;

    // stage W_mu f32 into the (future) H region
    {
        float* ws = (float*)(smem + H_OFF);
        for (int i = tid; i < 4096; i += 1024) ws[i] = W_mu[i];
    }
    __syncthreads();
    const float* wmu_s = (const float*)(smem + H_OFF);

    // W_mu bf16 region (swizzled), for the mean MFMA B-operand
    for (int i = tid; i < 2048; i += 1024) {
        const int col = i >> 6, k2 = (i & 63) * 2;
        const u32 p = pack2(wmu_s[col * HID + k2], wmu_s[col * HID + k2 + 1]);
        *(u32*)(smem + WMU_OFF + (((col << 8) + (k2 << 1)) ^ ((col & 7) << 4))) = p;
    }

    // weg = std * W_ihz * gate_scale (B-frags, K=32), all 4 q, in regs
    bf16x8 weg[4];
    {
        float stds[8];
        #pragma unroll
        for (int e = 0; e < 8; ++e) stds[e] = sqrtf(cov[lg * 8 + e]);
        const float gsc[4] = {L2E, L2E, L2E2, L2E};
        #pragma unroll
        for (int q = 0; q < 4; ++q) {
            const int col = q * 128 + wp * 16 + ln;
            bf16x8 v;
            #pragma unroll
            for (int e = 0; e < 8; ++e)
                v[e] = (short)f2bf(W_ih[col * KIN + 128 + lg * 8 + e] * stds[e] * gsc[q]);
            weg[q] = v;
        }
    }

    // Wr = (W_hh + W_ihz @ W_mu) * gate_scale -> LDS. half0: q{0,1}, half1: q{2,3}
    #pragma unroll
    for (int qq = 0; qq < 2; ++qq) {
        const int q = half * 2 + qq;
        const float gs = (q == 2) ? L2E2 : L2E;
        const int col = q * 128 + wp * 16 + ln;
        float wzf[32];
        #pragma unroll
        for (int j4 = 0; j4 < 8; ++j4)
            *(float4*)&wzf[j4 * 4] = *(const float4*)&W_ih[col * KIN + 128 + j4 * 4];
        #pragma unroll
        for (int ks = 0; ks < 4; ++ks) {
            float base[8];
            *(float4*)&base[0] = *(const float4*)&W_hh[col * HID + ks * 32 + lg * 8];
            *(float4*)&base[4] = *(const float4*)&W_hh[col * HID + ks * 32 + lg * 8 + 4];
            bf16x8 v;
            #pragma unroll
            for (int e = 0; e < 8; ++e) {
                float s = base[e];
                #pragma unroll
                for (int j = 0; j < 32; ++j)
                    s += wzf[j] * wmu_s[j * HID + ks * 32 + lg * 8 + e];
                v[e] = (short)f2bf(s * gs);
            }
            *(bf16x8*)(smem + WR_OFF + (((ks * 4 + q) * 8 + wp) << 10) + l * 16) = v;
        }
    }

    // mean-phase constants (meaningful for half==0 waves)
    const int rtm = (w >> 1) & 3, ctm = w & 1;
    const int zcol = ctm * 16 + ln;
    const float stdv = sqrtf(cov[zcol]);
    const float bmu  = b_mu[zcol];

    __syncthreads();   // Wr/WMU written; wmu_s reads done

    // zero h tile (overwrites wmu_s region) and E region
    for (int i = tid; i < 4096; i += 1024) ((u32*)(smem + H_OFF))[i] = 0;
    for (int i = tid; i < 1024; i += 1024) ((u32*)(smem + E_OFF))[i] = 0;

    const f32x4 vz4 = {0.f, 0.f, 0.f, 0.f};
    f32x4 cst[2] = {vz4, vz4};

    // eps load/store maps (thread -> (row, colpair) -> fragment-order byte)
    const int erow = tid >> 4, ecol = (tid & 15) * 2;
    const int ewr = ((erow >> 4) * 64 + (ecol >> 3) * 16 + (erow & 15)) * 16 + (ecol & 7) * 2;

    // loop-invariant LDS byte offsets
    int hrd[2];                 // H A-frag read base (col part added per ks)
    #pragma unroll
    for (int rt = 0; rt < 2; ++rt)
        hrd[rt] = hswz((half * 2 + rt) * 16 + ln, lg * 8);
    const int wrb = (wp << 10) + l * 16;          // Wr base (+ (ks*4+q)*8192)
    const int egb = E_OFF + ((half * 2) * 64 + l) * 16;  // E A-frag base (+rt*1024)

    __syncthreads();   // h zeros + E zeros visible

    for (int t = 0; t < T_STEPS; ++t) {
        // ---- P0: issue global loads (stay in flight across raw barA) ----
        uint4 xv[4];
        const uint4* xp = (const uint4*)xg
            + ((size_t)(t * 4 + bq) * 512 + wp * 64 + l) * 8 + half * 4;
        #pragma unroll
        for (int i = 0; i < 4; ++i) xv[i] = xp[i];
        const float2 fev = *(const float2*)(eps + ((size_t)t * BS_TOT + bs0 + erow) * LATD + ecol);

        // eg: eps_{t-1} @ weg^T (E reads first; ks0 operands land meanwhile)
        f32x4 acc[2][4];
        bf16x8 aE0 = *(const bf16x8*)(smem + egb);
        bf16x8 aE1 = *(const bf16x8*)(smem + egb + 1024);
        // preload ks0 gate operands
        bf16x8 a0[2], b0[4], a1[2], b1[4];
        #pragma unroll
        for (int rt = 0; rt < 2; ++rt)
            a0[rt] = *(const bf16x8*)(smem + H_OFF + hrd[rt]);
        #pragma unroll
        for (int q = 0; q < 4; ++q)
            b0[q] = *(const bf16x8*)(smem + WR_OFF + wrb + q * 8192);
        #pragma unroll
        for (int q = 0; q < 4; ++q) {
            acc[0][q] = __builtin_amdgcn_mfma_f32_16x16x32_bf16(aE0, weg[q], vz4, 0, 0, 0);
            acc[1][q] = __builtin_amdgcn_mfma_f32_16x16x32_bf16(aE1, weg[q], vz4, 0, 0, 0);
        }
        // gates: pipelined over ks (prefetch ks+1 before MFMAs of ks)
        #pragma unroll
        for (int ks = 0; ks < 4; ++ks) {
            if (ks < 3) {
                #pragma unroll
                for (int rt = 0; rt < 2; ++rt)
                    a1[rt] = *(const bf16x8*)(smem + H_OFF + (hrd[rt] ^ 0) + ((hswz((half*2+rt)*16+ln, (ks+1)*32 + lg*8)) - hrd[rt]));
                #pragma unroll
                for (int q = 0; q < 4; ++q)
                    b1[q] = *(const bf16x8*)(smem + WR_OFF + wrb + ((ks + 1) * 4 + q) * 8192);
            }
            #pragma unroll
            for (int rt = 0; rt < 2; ++rt)
                #pragma unroll
                for (int q = 0; q < 4; ++q)
                    acc[rt][q] = __builtin_amdgcn_mfma_f32_16x16x32_bf16(
                        a0[rt], b0[q], acc[rt][q], 0, 0, 0);
            #pragma unroll
            for (int rt = 0; rt < 2; ++rt) a0[rt] = a1[rt];
            #pragma unroll
            for (int q = 0; q < 4; ++q) b0[q] = b1[q];
        }
        // mean/z for t-1 (half0 waves, off critical path)
        if (half == 0 && t > 0) {
            f32x4 macc = vz4;
            #pragma unroll
            for (int ks = 0; ks < 4; ++ks) {
                const bf16x8 am = *(const bf16x8*)(smem + H_OFF + hswz(rtm * 16 + ln, ks * 32 + lg * 8));
                const bf16x8 bm = *(const bf16x8*)(smem + WMU_OFF + hswz(zcol, ks * 32 + lg * 8));
                macc = __builtin_amdgcn_mfma_f32_16x16x32_bf16(am, bm, macc, 0, 0, 0);
            }
            #pragma unroll
            for (int e = 0; e < 4; ++e) {
                const int row = rtm * 16 + lg * 4 + e;
                const int eb = (rtm * 64 + (zcol >> 3) * 16 + (lg * 4 + e)) * 16 + (zcol & 7) * 2;
                const float evv = bf2f(*(const uint16_t*)(smem + E_OFF + eb));
                out[(size_t)(bs0 + row) * 6400 + (t - 1) * 32 + zcol] =
                    macc[e] + bmu + evv * stdv;
            }
        }

        BAR();   // barA: LDS reads of P0 done; global loads still in flight

        // ---- P1: store eps_t into E (for step t+1) ----
        *(u32*)(smem + E_OFF + ewr) = cvt_pk_bf16(fev.x, fev.y);

        // LSTM elementwise (gates pre-scaled by log2e / 2log2e)
        #pragma unroll
        for (int rt = 0; rt < 2; ++rt) {
            const uint4 u01 = xv[2 * rt], u23 = xv[2 * rt + 1];
            const float xi[4] = { bf2f(u01.x & 0xffff), bf2f(u01.x >> 16),
                                  bf2f(u01.y & 0xffff), bf2f(u01.y >> 16) };
            const float xf[4] = { bf2f(u01.z & 0xffff), bf2f(u01.z >> 16),
                                  bf2f(u01.w & 0xffff), bf2f(u01.w >> 16) };
            const float xgv[4] = { bf2f(u23.x & 0xffff), bf2f(u23.x >> 16),
                                   bf2f(u23.y & 0xffff), bf2f(u23.y >> 16) };
            const float xo[4] = { bf2f(u23.z & 0xffff), bf2f(u23.z >> 16),
                                  bf2f(u23.w & 0xffff), bf2f(u23.w >> 16) };
            #pragma unroll
            for (int e = 0; e < 4; ++e) {
                const float iv = acc[rt][0][e] + xi[e];
                const float fv = acc[rt][1][e] + xf[e];
                const float gv = acc[rt][2][e] + xgv[e];
                const float ov = acc[rt][3][e] + xo[e];
                const float c  = sig2(fv) * cst[rt][e] + sig2(iv) * tanh2(gv);
                cst[rt][e] = c;
                const float h = sig2(ov) * tanh2(c * L2E2);
                const int row = (half * 2 + rt) * 16 + lg * 4 + e;
                *(uint16_t*)(smem + H_OFF + hswz(row, wp * 16 + ln)) = f2bf(h);
            }
        }

        BAR();   // barB: h_t + eps_t visible
    }

    // epilogue: z for t = 199 (E holds eps_199, h holds h_199)
    if (half == 0) {
        f32x4 macc = vz4;
        #pragma unroll
        for (int ks = 0; ks < 4; ++ks) {
            const bf16x8 am = *(const bf16x8*)(smem + H_OFF + hswz(rtm * 16 + ln, ks * 32 + lg * 8));
            const bf16x8 bm = *(const bf16x8*)(smem + WMU_OFF + hswz(zcol, ks * 32 + lg * 8));
            macc = __builtin_amdgcn_mfma_f32_16x16x32_bf16(am, bm, macc, 0, 0, 0);
        }
        #pragma unroll
        for (int e = 0; e < 4; ++e) {
            const int row = rtm * 16 + lg * 4 + e;
            const int eb = (rtm * 64 + (zcol >> 3) * 16 + (lg * 4 + e)) * 16 + (zcol & 7) * 2;
            const float evv = bf2f(*(const uint16_t*)(smem + E_OFF + eb));
            out[(size_t)(bs0 + row) * 6400 + 199 * 32 + zcol] =
                macc[e] + bmu + evv * stdv;
        }
    }
}

extern "C" void kernel_launch(void* const* d_in, const int* in_sizes, int n_in,
                              void* d_out, int out_size, void* d_ws, size_t ws_size,
                              hipStream_t stream) {
    const float* x    = (const float*)d_in[0];
    const float* eps  = (const float*)d_in[1];
    const float* W_ih = (const float*)d_in[2];
    const float* W_hh = (const float*)d_in[3];
    const float* b_ih = (const float*)d_in[4];
    const float* b_hh = (const float*)d_in[5];
    const float* W_mu = (const float*)d_in[6];
    const float* b_mu = (const float*)d_in[7];
    const float* cov  = (const float*)d_in[8];
    float* out = (float*)d_out;
    uint16_t* xg = (uint16_t*)d_ws;   // 52,428,800 bytes

    hipLaunchKernelGGL(xg_prep, dim3(800), dim3(512), 0, stream, x, W_ih, b_ih, b_hh, b_mu, xg);
    hipLaunchKernelGGL(lp_ent, dim3(800), dim3(256), 0, stream, eps, cov, out);
    hipLaunchKernelGGL(lstm_main, dim3(200), dim3(1024), 0, stream,
                       eps, W_ih, W_hh, W_mu, b_mu, cov, xg, out);
}